// Round 4
// baseline (4230.112 us; speedup 1.0000x reference)
//
#include <hip/hip_runtime.h>

// GPT-2 forward (B=4,T=1024,C=768,H=12,L=12,V=50257) on gfx950.
// bf16 MFMA GEMMs (fp32 accum), fp32 residual stream / LN / softmax stats.

#define LNUM 12
#define BB   4
#define TT   1024
#define CC   768
#define HH   12
#define VV   50257
#define HSZ  64
#define MM   (BB*TT)      // 4096
#define VPAD 50304        // 393*128
#define QK_SCALE 0.125f   // 1/sqrt(64)

typedef __attribute__((ext_vector_type(4))) float f32x4;
typedef __attribute__((ext_vector_type(8))) short bf16x8;
typedef __attribute__((ext_vector_type(4))) short bf16x4;
typedef unsigned short u16;
typedef unsigned int   u32;

__device__ __forceinline__ u16 f2bf(float f) {
  union { float f; u32 u; } v; v.f = f;
  u32 u = v.u;
  u32 r = (u + 0x7fffu + ((u >> 16) & 1u)) >> 16;   // round-nearest-even
  return (u16)r;
}

// async 16B global->LDS (linear dest: base + lane*16)
__device__ __forceinline__ void g2lds16(const u16* g, u16* s) {
  __builtin_amdgcn_global_load_lds(
      (const __attribute__((address_space(1))) u32*)(const void*)g,
      (__attribute__((address_space(3))) u32*)(void*)s, 16, 0, 0);
}

// byte offset of logical 16B-chunk `c` of row `row` in a [rows][64 bf16] tile,
// XOR-swizzled: content chunk c lives at block (c ^ (row&7)).
__device__ __forceinline__ int swz(int row, int c) {
  return row * 128 + ((c ^ (row & 7)) << 4);
}

// ---------------------------------------------------------------- weight prep
__global__ __launch_bounds__(256) void k_convert_pad(
    const float* __restrict__ in, u16* __restrict__ out, long n_in, long n_tot) {
  long i = ((long)blockIdx.x * 256 + threadIdx.x) * 4;
  if (i >= n_tot) return;
  if (i + 4 <= n_in) {
    float4 v = *(const float4*)(in + i);
    bf16x4 r = { (short)f2bf(v.x), (short)f2bf(v.y), (short)f2bf(v.z), (short)f2bf(v.w) };
    *(bf16x4*)(out + i) = r;
  } else {
    for (int j = 0; j < 4; ++j) out[i + j] = 0;   // pad region (n_in % 4 == 0)
  }
}

// in: [L][K][N] fp32  ->  out: [L][N][K] bf16
__global__ __launch_bounds__(256) void k_transpose(
    const float* __restrict__ in, u16* __restrict__ out, int K, int N) {
  __shared__ float tile[32][33];
  size_t off = (size_t)blockIdx.z * K * N;
  const float* ip = in + off;
  u16* op = out + off;
  int n0 = blockIdx.x * 32, k0 = blockIdx.y * 32;
  int tx = threadIdx.x & 31, ty = threadIdx.x >> 5;     // 32 x 8
  for (int i = 0; i < 32; i += 8)
    tile[ty + i][tx] = ip[(size_t)(k0 + ty + i) * N + n0 + tx];
  __syncthreads();
  for (int i = 0; i < 32; i += 8)
    op[(size_t)(n0 + ty + i) * K + k0 + tx] = f2bf(tile[tx][ty + i]);
}

// ---------------------------------------------------------------- embedding
__global__ __launch_bounds__(192) void k_embed(
    const int* __restrict__ inp, const float* __restrict__ wte,
    const float* __restrict__ wpe, float* __restrict__ x) {
  int m = blockIdx.x;            // token row 0..4095
  int t = m & (TT - 1);
  int tok = inp[m];
  const float4* a = (const float4*)(wte + (size_t)tok * CC);
  const float4* p = (const float4*)(wpe + (size_t)t * CC);
  float4* xr = (float4*)(x + (size_t)m * CC);
  int c = threadIdx.x;           // 0..191, CC/4 = 192 float4s
  float4 va = a[c], vp = p[c];
  xr[c] = make_float4(va.x + vp.x, va.y + vp.y, va.z + vp.z, va.w + vp.w);
}

// ---------------------------------------------------------------- layernorm
__global__ __launch_bounds__(256) void k_ln(
    const float* __restrict__ x, const float* __restrict__ g,
    const float* __restrict__ b, u16* __restrict__ out) {
  int row = blockIdx.x;
  const float* xr = x + (size_t)row * CC;
  int tid = threadIdx.x, lane = tid & 63, wid = tid >> 6;
  float v0 = xr[tid], v1 = xr[tid + 256], v2 = xr[tid + 512];
  float s = v0 + v1 + v2;
  float q = v0 * v0 + v1 * v1 + v2 * v2;
  for (int o = 1; o < 64; o <<= 1) { s += __shfl_xor(s, o); q += __shfl_xor(q, o); }
  __shared__ float rs[4], rq[4];
  if (lane == 0) { rs[wid] = s; rq[wid] = q; }
  __syncthreads();
  s = rs[0] + rs[1] + rs[2] + rs[3];
  q = rq[0] + rq[1] + rq[2] + rq[3];
  float mu  = s * (1.0f / CC);
  float inv = rsqrtf(q * (1.0f / CC) - mu * mu + 1e-5f);
  u16* orow = out + (size_t)row * CC;
  orow[tid]       = f2bf((v0 - mu) * inv * g[tid]       + b[tid]);
  orow[tid + 256] = f2bf((v1 - mu) * inv * g[tid + 256] + b[tid + 256]);
  orow[tid + 512] = f2bf((v2 - mu) * inv * g[tid + 512] + b[tid + 512]);
}

// ---------------------------------------------------------------- GEMM
// C[M,N] = A[M,K] (bf16) * Bt[N,K]^T (bf16), fp32 accum, fused epilogues.
// EPI: 0 = QKV split-scatter, 1 = bias+residual into fp32 x, 2 = bias+GELU->bf16, 3 = head->fp32 out
// NSPLIT: split-K factor (EPI=1 only; partial sums via fp32 atomicAdd into x).
template <int EPI, int NSPLIT>
__global__ __launch_bounds__(256, 2) void k_gemm(
    const u16* __restrict__ A, const u16* __restrict__ Bt, const float* __restrict__ bias,
    float* __restrict__ xio, u16* __restrict__ obf, float* __restrict__ ohead,
    u16* __restrict__ Qb, u16* __restrict__ Kb, u16* __restrict__ VTb,
    int N, int K) {
  __shared__ __align__(16) u16 As[128 * 64];
  __shared__ __align__(16) u16 Bs[128 * 64];
  int tid = threadIdx.x, wid = tid >> 6, lane = tid & 63;
  int lr = lane & 15, lg = lane >> 4;
  int m0 = blockIdx.y * 128, n0 = blockIdx.x * 128;
  int wr = (wid >> 1) * 64, wc = (wid & 1) * 64;
  int KS = K / NSPLIT;
  int kbeg = (NSPLIT > 1) ? blockIdx.z * KS : 0;

  f32x4 acc[4][4];
#pragma unroll
  for (int i = 0; i < 4; ++i)
#pragma unroll
    for (int j = 0; j < 4; ++j) acc[i][j] = (f32x4){0.f, 0.f, 0.f, 0.f};

  int srow = lane >> 3;      // 0..7 within a 1KB issue
  int scb  = lane & 7;       // 16B chunk within a 128B row

  for (int k0 = kbeg; k0 < kbeg + KS; k0 += 64) {
#pragma unroll
    for (int i = 0; i < 4; ++i) {
      int r  = (wid * 4 + i) * 8 + srow;          // tile row 0..127
      int cg = scb ^ (r & 7);                     // pre-swizzled source chunk
      g2lds16(A  + ((size_t)(m0 + r) * K + k0 + cg * 8), As + (wid * 4 + i) * 512);
      g2lds16(Bt + ((size_t)(n0 + r) * K + k0 + cg * 8), Bs + (wid * 4 + i) * 512);
    }
    __syncthreads();

    bf16x8 af[4][2], bfr[4][2];
#pragma unroll
    for (int mi = 0; mi < 4; ++mi) {
      int r = wr + mi * 16 + lr;
#pragma unroll
      for (int ks = 0; ks < 2; ++ks)
        af[mi][ks] = *(const bf16x8*)((const char*)As + swz(r, ks * 4 + lg));
    }
#pragma unroll
    for (int ni = 0; ni < 4; ++ni) {
      int r = wc + ni * 16 + lr;
#pragma unroll
      for (int ks = 0; ks < 2; ++ks)
        bfr[ni][ks] = *(const bf16x8*)((const char*)Bs + swz(r, ks * 4 + lg));
    }
#pragma unroll
    for (int ks = 0; ks < 2; ++ks)
#pragma unroll
      for (int mi = 0; mi < 4; ++mi)
#pragma unroll
        for (int ni = 0; ni < 4; ++ni)
          acc[mi][ni] = __builtin_amdgcn_mfma_f32_16x16x32_bf16(
              af[mi][ks], bfr[ni][ks], acc[mi][ni], 0, 0, 0);
    __syncthreads();
  }

#pragma unroll
  for (int mi = 0; mi < 4; ++mi)
#pragma unroll
    for (int ni = 0; ni < 4; ++ni) {
      f32x4 a = acc[mi][ni];
#pragma unroll
      for (int j = 0; j < 4; ++j) {
        int m = m0 + wr + mi * 16 + lg * 4 + j;
        int n = n0 + wc + ni * 16 + lr;
        float v = a[j];
        if constexpr (EPI == 3) {
          if (n < VV) ohead[(size_t)m * VV + n] = v;
        } else if constexpr (EPI == 1) {
          if (NSPLIT == 1 || blockIdx.z == 0) v += bias[n];
          if constexpr (NSPLIT > 1) atomicAdd(&xio[(size_t)m * N + n], v);
          else                      xio[(size_t)m * N + n] += v;
        } else {
          v += bias[n];
          if constexpr (EPI == 0) {
            int hh = n / 192, r = n - hh * 192;
            int bb = m >> 10, t = m & (TT - 1);
            size_t bh = (size_t)bb * HH + hh;
            if (r < 64)        Qb [(bh * TT + t) * HSZ + r]         = f2bf(v);
            else if (r < 128)  Kb [(bh * TT + t) * HSZ + (r - 64)]  = f2bf(v);
            else               VTb[(bh * HSZ + (r - 128)) * TT + t] = f2bf(v);
          } else {  // EPI == 2: exact GELU
            float gv = 0.5f * v * (1.0f + erff(v * 0.70710678118f));
            obf[(size_t)m * N + n] = f2bf(gv);
          }
        }
      }
    }
}

// ---------------------------------------------------------------- attention
// Flash-style causal attention. Grid: (T/64, B*H). 4 waves; wave w owns 16 q-rows.
// qx reversed so heavy (high-q) blocks dispatch first -> better tail packing.
__global__ __launch_bounds__(256, 2) void k_attn(
    const u16* __restrict__ Qb, const u16* __restrict__ Kb,
    const u16* __restrict__ VTb, u16* __restrict__ atty) {
  __shared__ __align__(16) u16 Ks[64 * 64];
  __shared__ __align__(16) u16 Vs[64 * 64];      // [d][t_local]
  __shared__ __align__(16) u16 Ps[4][16 * 64];   // per-wave P tile
  int bh = blockIdx.y;
  int bi = bh / HH, hi = bh - bi * HH;
  int qx = gridDim.x - 1 - blockIdx.x;           // heavy tiles first
  int q0 = qx * 64;
  int tid = threadIdx.x, wid = tid >> 6, lane = tid & 63;
  int lr = lane & 15, lg = lane >> 4;
  const u16* Qg = Qb  + (size_t)bh * TT * HSZ;
  const u16* Kg = Kb  + (size_t)bh * TT * HSZ;
  const u16* Vg = VTb + (size_t)bh * HSZ * TT;   // [d][t]

  int qfr = q0 + wid * 16 + lr;                  // this lane's A-frag q row
  bf16x8 qf[2];
  qf[0] = *(const bf16x8*)(Qg + (size_t)qfr * HSZ + lg * 8);
  qf[1] = *(const bf16x8*)(Qg + (size_t)qfr * HSZ + 32 + lg * 8);

  f32x4 o[4];
#pragma unroll
  for (int i = 0; i < 4; ++i) o[i] = (f32x4){0.f, 0.f, 0.f, 0.f};
  float mrow[4] = {-3.0e38f, -3.0e38f, -3.0e38f, -3.0e38f};
  float lrow[4] = {0.f, 0.f, 0.f, 0.f};

  int wqmax = q0 + wid * 16 + 15;
  int nkv = qx + 1;
  for (int kv = 0; kv < nkv; ++kv) {
    int k0 = kv * 64;
    // stage K [trow][d] and V^T [d][trow] tiles, XOR-swizzled
#pragma unroll
    for (int i = 0; i < 2; ++i) {
      int blk = tid + i * 256;                   // 0..511
      int r = blk >> 3, cb = blk & 7;
      *(bf16x8*)((char*)Ks + swz(r, cb)) = *(const bf16x8*)(Kg + (size_t)(k0 + r) * HSZ + cb * 8);
      *(bf16x8*)((char*)Vs + swz(r, cb)) = *(const bf16x8*)(Vg + (size_t)r * TT + k0 + cb * 8);
    }
    __syncthreads();

    if (k0 <= wqmax) {                           // wave-uniform causal skip
      f32x4 s[4];
#pragma unroll
      for (int ni = 0; ni < 4; ++ni) {
        s[ni] = (f32x4){0.f, 0.f, 0.f, 0.f};
#pragma unroll
        for (int ks = 0; ks < 2; ++ks) {
          int rr = ni * 16 + lr;
          bf16x8 kf = *(const bf16x8*)((const char*)Ks + swz(rr, ks * 4 + lg));
          s[ni] = __builtin_amdgcn_mfma_f32_16x16x32_bf16(qf[ks], kf, s[ni], 0, 0, 0);
        }
      }
      float alpha[4];
#pragma unroll
      for (int j = 0; j < 4; ++j) {
        int qr = q0 + wid * 16 + lg * 4 + j;
        float mx = -3.0e38f;
#pragma unroll
        for (int ni = 0; ni < 4; ++ni) {
          float v = s[ni][j] * QK_SCALE;
          if (k0 + ni * 16 + lr > qr) v = -1.0e30f;
          s[ni][j] = v;
          mx = fmaxf(mx, v);
        }
        mx = fmaxf(mx, __shfl_xor(mx, 1));
        mx = fmaxf(mx, __shfl_xor(mx, 2));
        mx = fmaxf(mx, __shfl_xor(mx, 4));
        mx = fmaxf(mx, __shfl_xor(mx, 8));
        float mn = fmaxf(mrow[j], mx);
        alpha[j] = __expf(mrow[j] - mn);
        mrow[j] = mn;
        float ls = 0.f;
#pragma unroll
        for (int ni = 0; ni < 4; ++ni) {
          float pv = __expf(s[ni][j] - mn);
          s[ni][j] = pv;
          ls += pv;
        }
        ls += __shfl_xor(ls, 1);
        ls += __shfl_xor(ls, 2);
        ls += __shfl_xor(ls, 4);
        ls += __shfl_xor(ls, 8);
        lrow[j] = lrow[j] * alpha[j] + ls;
#pragma unroll
        for (int di = 0; di < 4; ++di) o[di][j] *= alpha[j];
      }
      // write P (bf16) to per-wave swizzled LDS, re-read as A-fragments
      char* Pw = (char*)&Ps[wid][0];
#pragma unroll
      for (int ni = 0; ni < 4; ++ni)
#pragma unroll
        for (int j = 0; j < 4; ++j) {
          int pr = lg * 4 + j, pc = ni * 16 + lr;
          *(u16*)(Pw + swz(pr, pc >> 3) + (pc & 7) * 2) = f2bf(s[ni][j]);
        }
#pragma unroll
      for (int di = 0; di < 4; ++di)
#pragma unroll
        for (int ks = 0; ks < 2; ++ks) {
          bf16x8 pa = *(const bf16x8*)(Pw + swz(lr, ks * 4 + lg));
          int vr = di * 16 + lr;
          bf16x8 vf = *(const bf16x8*)((const char*)Vs + swz(vr, ks * 4 + lg));
          o[di] = __builtin_amdgcn_mfma_f32_16x16x32_bf16(pa, vf, o[di], 0, 0, 0);
        }
    }
    __syncthreads();
  }

#pragma unroll
  for (int j = 0; j < 4; ++j) {
    float inv = 1.0f / lrow[j];
    int t = q0 + wid * 16 + lg * 4 + j;
    size_t base = ((size_t)bi * TT + t) * CC + hi * HSZ;
#pragma unroll
    for (int di = 0; di < 4; ++di)
      atty[base + di * 16 + lr] = f2bf(o[di][j] * inv);
  }
}

// ---------------------------------------------------------------- launch
extern "C" void kernel_launch(void* const* d_in, const int* in_sizes, int n_in,
                              void* d_out, int out_size, void* d_ws, size_t ws_size,
                              hipStream_t stream) {
  const int*   inp  = (const int*)d_in[0];
  const float* wte  = (const float*)d_in[1];
  const float* wpe  = (const float*)d_in[2];
  const float* ln1g = (const float*)d_in[3];
  const float* ln1b = (const float*)d_in[4];
  const float* wqkv = (const float*)d_in[5];
  const float* bqkv = (const float*)d_in[6];
  const float* wout = (const float*)d_in[7];
  const float* bout = (const float*)d_in[8];
  const float* ln2g = (const float*)d_in[9];
  const float* ln2b = (const float*)d_in[10];
  const float* wfc1 = (const float*)d_in[11];
  const float* bfc1 = (const float*)d_in[12];
  const float* wfc2 = (const float*)d_in[13];
  const float* bfc2 = (const float*)d_in[14];
  const float* lnfg = (const float*)d_in[15];
  const float* lnfb = (const float*)d_in[16];
  float* out = (float*)d_out;

  char* p = (char*)d_ws;
  auto alloc = [&](size_t n) { char* r = p; p += (n + 255) & ~(size_t)255; return r; };
  u16*   wteb  = (u16*)alloc((size_t)VPAD * CC * 2);
  u16*   wqkvT = (u16*)alloc((size_t)LNUM * 3 * CC * CC * 2);
  u16*   woutT = (u16*)alloc((size_t)LNUM * CC * CC * 2);
  u16*   wfc1T = (u16*)alloc((size_t)LNUM * 4 * CC * CC * 2);
  u16*   wfc2T = (u16*)alloc((size_t)LNUM * 4 * CC * CC * 2);
  float* x     = (float*)alloc((size_t)MM * CC * 4);
  u16*   h     = (u16*)alloc((size_t)MM * CC * 2);
  u16*   Qb    = (u16*)alloc((size_t)BB * HH * TT * HSZ * 2);
  u16*   Kb    = (u16*)alloc((size_t)BB * HH * TT * HSZ * 2);
  u16*   VTb   = (u16*)alloc((size_t)BB * HH * TT * HSZ * 2);
  u16*   atty  = (u16*)alloc((size_t)MM * CC * 2);
  u16*   fc1   = (u16*)alloc((size_t)MM * 4 * CC * 2);

  // weight prep (same work every call)
  {
    long nin = (long)VV * CC, ntot = (long)VPAD * CC;
    k_convert_pad<<<(unsigned)((ntot / 4 + 255) / 256), 256, 0, stream>>>(wte, wteb, nin, ntot);
  }
  k_transpose<<<dim3(3 * CC / 32, CC / 32, LNUM), 256, 0, stream>>>(wqkv, wqkvT, CC, 3 * CC);
  k_transpose<<<dim3(CC / 32, CC / 32, LNUM), 256, 0, stream>>>(wout, woutT, CC, CC);
  k_transpose<<<dim3(4 * CC / 32, CC / 32, LNUM), 256, 0, stream>>>(wfc1, wfc1T, CC, 4 * CC);
  k_transpose<<<dim3(CC / 32, 4 * CC / 32, LNUM), 256, 0, stream>>>(wfc2, wfc2T, 4 * CC, CC);

  k_embed<<<MM, 192, 0, stream>>>(inp, wte, wpe, x);

  for (int l = 0; l < LNUM; ++l) {
    k_ln<<<MM, 256, 0, stream>>>(x, ln1g + l * CC, ln1b + l * CC, h);
    k_gemm<0, 1><<<dim3(3 * CC / 128, MM / 128), 256, 0, stream>>>(
        h, wqkvT + (size_t)l * 3 * CC * CC, bqkv + l * 3 * CC,
        nullptr, nullptr, nullptr, Qb, Kb, VTb, 3 * CC, CC);
    k_attn<<<dim3(TT / 64, BB * HH), 256, 0, stream>>>(Qb, Kb, VTb, atty);
    k_gemm<1, 2><<<dim3(CC / 128, MM / 128, 2), 256, 0, stream>>>(
        atty, woutT + (size_t)l * CC * CC, bout + l * CC,
        x, nullptr, nullptr, nullptr, nullptr, nullptr, CC, CC);
    k_ln<<<MM, 256, 0, stream>>>(x, ln2g + l * CC, ln2b + l * CC, h);
    k_gemm<2, 1><<<dim3(4 * CC / 128, MM / 128), 256, 0, stream>>>(
        h, wfc1T + (size_t)l * 4 * CC * CC, bfc1 + l * 4 * CC,
        nullptr, fc1, nullptr, nullptr, nullptr, nullptr, 4 * CC, CC);
    k_gemm<1, 2><<<dim3(CC / 128, MM / 128, 2), 256, 0, stream>>>(
        fc1, wfc2T + (size_t)l * 4 * CC * CC, bfc2 + l * CC,
        x, nullptr, nullptr, nullptr, nullptr, nullptr, CC, 4 * CC);
  }

  k_ln<<<MM, 256, 0, stream>>>(x, lnfg, lnfb, h);
  k_gemm<3, 1><<<dim3(VPAD / 128, MM / 128), 256, 0, stream>>>(
      h, wteb, nullptr, nullptr, nullptr, out,
      nullptr, nullptr, nullptr, VPAD, CC);
}